// Round 8
// baseline (382.865 us; speedup 1.0000x reference)
//
#include <hip/hip_runtime.h>
#include <hip/hip_bf16.h>
#include <type_traits>

using bf16 = __hip_bfloat16;
typedef float f32x4 __attribute__((ext_vector_type(4)));
typedef __bf16 bf16x8_t __attribute__((ext_vector_type(8)));
typedef short  s16x8_t  __attribute__((ext_vector_type(8)));

template <typename V, typename = void> struct MfmaWorks : std::false_type {};
template <typename V>
struct MfmaWorks<V, std::void_t<decltype(__builtin_amdgcn_mfma_f32_16x16x32_bf16(
    std::declval<V>(), std::declval<V>(), std::declval<f32x4>(), 0, 0, 0))>> : std::true_type {};
using frag_t = std::conditional_t<MfmaWorks<bf16x8_t>::value, bf16x8_t, s16x8_t>;

template <typename V>
__device__ __forceinline__ f32x4 mfma_16x16x32(V a, V b, f32x4 c) {
    return __builtin_amdgcn_mfma_f32_16x16x32_bf16(a, b, c, 0, 0, 0);
}

__device__ __forceinline__ void gld_lds16(const void* g, void* l) {
    __builtin_amdgcn_global_load_lds(
        (const __attribute__((address_space(1))) unsigned int*)g,
        (__attribute__((address_space(3))) unsigned int*)l, 16, 0, 0);
}

// pack two f32 -> u32 of 2 bf16 (lo first); compiler fuses to v_cvt_pk_bf16_f32
__device__ __forceinline__ unsigned pack2(float lo, float hi) {
    bf16 a = __float2bfloat16(lo), b = __float2bfloat16(hi);
    unsigned short al, bl;
    __builtin_memcpy(&al, &a, 2);
    __builtin_memcpy(&bl, &b, 2);
    return (unsigned)al | ((unsigned)bl << 16);
}

// ---------- runtime-dtype input loader: flag==1 -> f32, flag==0 -> bf16 ----------
__device__ __forceinline__ float ldin(const void* p, long i, int f32) {
    return f32 ? ((const float*)p)[i] : __bfloat162float(((const bf16*)p)[i]);
}

// Probe (proven in r4/r5): even-indexed bf16 reads; real bf16 ~100% sane, f32-low-halves ~8%.
__global__ void detect_dtype(const void* __restrict__ inp, int* __restrict__ flag)
{
    const int t = threadIdx.x;  // 64
    int sane_cnt = 0;
#pragma unroll
    for (int s = 0; s < 4; s++) {
        float v = __bfloat162float(((const bf16*)inp)[2 * (t + 64 * s)]);
        float a = fabsf(v);
        bool sane = (a == 0.f) || (a > 9e-4f && a < 1000.f);
        unsigned long long m = __ballot(sane);
        sane_cnt += (int)__popcll(m);
    }
    if (t == 0) *flag = (sane_cnt > 128) ? 0 : 1;
}

// merged input conversions: blocks [0,2048) -> inpB from inp; [2048,6144) -> ctxB from x|y
__global__ __launch_bounds__(256)
void cvt_in(const void* __restrict__ inp, const void* __restrict__ x,
            const void* __restrict__ y, bf16* __restrict__ inpB,
            bf16* __restrict__ ctxB, const int* __restrict__ flag)
{
    const int f = *flag;
    if (blockIdx.x < 2048) {
        const long i0 = ((long)blockIdx.x * 256 + threadIdx.x) * 8;   // < 4,194,304
#pragma unroll
        for (int u = 0; u < 8; u++)
            inpB[i0 + u] = __float2bfloat16(ldin(inp, i0 + u, f));
    } else {
        const long i0 = ((long)(blockIdx.x - 2048) * 256 + threadIdx.x) * 8;  // < 8,388,608
        const long r = i0 >> 9, c0 = i0 & 511;
        const long b = r >> 11, jj = r & 2047;
        const void* src = (jj < 1024) ? x : y;
        const long  soff = (jj < 1024) ? ((b * 1024 + jj) * 512 + c0)
                                       : ((b * 1024 + (jj - 1024)) * 512 + c0);
#pragma unroll
        for (int u = 0; u < 8; u++)
            ctxB[i0 + u] = __float2bfloat16(ldin(src, soff + u, f));
    }
}

// ---------------------------------------------------------------------------
// ONE prep kernel: all weight/bias conversions + WfT build + memory-token /
// zero prefill of kb, Skb, GTS-SvT, SvC (directly from raw inputs).
// blocks: [0,512) weights | [512,1634) WfT | [1634,1637) biases |
//         [1637,1893) kb j>=2048 | [1893,2149) Skb j>=1024 | [2149,2213) SvT+SvC
// ---------------------------------------------------------------------------
__global__ __launch_bounds__(256)
void prep(const void* __restrict__ Wq, const void* __restrict__ Wkv,
          const void* __restrict__ Wo, const void* __restrict__ Wf,
          const void* __restrict__ bff, const void* __restrict__ bq,
          const void* __restrict__ bkv, const void* __restrict__ bo,
          const void* __restrict__ mk, const void* __restrict__ Smk,
          const void* __restrict__ Smv,
          bf16* __restrict__ WqB, bf16* __restrict__ WkvB, bf16* __restrict__ WoB,
          bf16* __restrict__ WfT, bf16* __restrict__ bqB, bf16* __restrict__ bkvB,
          bf16* __restrict__ boB, bf16* __restrict__ kb, bf16* __restrict__ Skb,
          bf16* __restrict__ GTS, bf16* __restrict__ SvC,
          const int* __restrict__ flag, float qscale)
{
    const int f = *flag;
    const int blk = blockIdx.x;
    const int t = threadIdx.x;
    const float SQRT3 = 1.7320508f;

    if (blk < 512) {
        long id = (long)blk * 256 + t;
        const void* src; bf16* dst; float sc;
        if (blk < 128)      { src = Wq;  dst = WqB;  sc = qscale; }
        else if (blk < 384) { src = Wkv; dst = WkvB; sc = 1.f; id -= 128L * 256; }
        else                { src = Wo;  dst = WoB;  sc = 1.f; id -= 384L * 256; }
        const long i0 = id * 8;
#pragma unroll
        for (int u = 0; u < 8; u++)
            dst[i0 + u] = __float2bfloat16(sc * ldin(src, i0 + u, f));
    } else if (blk < 1634) {
        // WfT[2176][1056]: WfT[j][r] = (j<2051 && r<1027) ? Wf[r][j]
        //                 : (j==2051 && r<1027) ? bf[r] : 0   (bias ones-row trick)
        const long i0 = ((long)(blk - 512) * 256 + t) * 8;  // < 2,297,856
        if (i0 >= 2176L * 1056) return;
        const long j = i0 / 1056, r0 = i0 % 1056;
        __align__(16) bf16 tmp[8];
#pragma unroll
        for (int u = 0; u < 8; u++) {
            const long r = r0 + u;
            float v = 0.f;
            if (r < 1027) {
                if (j < 2051)       v = ldin(Wf, r * 2051 + j, f);
                else if (j == 2051) v = ldin(bff, r, f);
            }
            tmp[u] = __float2bfloat16(v);
        }
        *(uint4*)(WfT + i0) = *(const uint4*)tmp;
    } else if (blk < 1637) {
        const void* src; bf16* dst; int n; float sc;
        switch (blk - 1634) {
            case 0:  src = bq;  dst = bqB;  n = 512;  sc = qscale; break;
            case 1:  src = bkv; dst = bkvB; n = 1024; sc = 1.f;    break;
            default: src = bo;  dst = boB;  n = 512;  sc = 1.f;    break;
        }
        for (int i = t; i < n; i += 256)
            dst[i] = __float2bfloat16(sc * ldin(src, i, f));
    } else if (blk < 1893) {
        // kb[bh][2048+jj][dg]: jj<3 -> 8*m_k; else 0
        const long e = ((long)(blk - 1637) * 256 + t) * 8;   // < 524288
        const long bh = e >> 13, rem = e & 8191;
        const long jj = rem >> 6, dg0 = rem & 63;
        const long h = bh & 7;
        __align__(16) bf16 tmp[8];
#pragma unroll
        for (int u = 0; u < 8; u++) {
            float v = (jj < 3) ? 8.f * ldin(mk, jj * 512 + h * 64 + dg0 + u, f) : 0.f;
            tmp[u] = __float2bfloat16(v);
        }
        *(uint4*)(kb + (bh * 2176 + 2048 + jj) * 64 + dg0) = *(const uint4*)tmp;
    } else if (blk < 2149) {
        // Skb[bh][1024+jj][dg]: jj<3 -> 8*Sm_k; else 0
        const long e = ((long)(blk - 1893) * 256 + t) * 8;   // < 524288
        const long bh = e >> 13, rem = e & 8191;
        const long jj = rem >> 6, dg0 = rem & 63;
        const long h = bh & 7;
        __align__(16) bf16 tmp[8];
#pragma unroll
        for (int u = 0; u < 8; u++) {
            float v = (jj < 3) ? 8.f * ldin(Smk, jj * 512 + h * 64 + dg0 + u, f) : 0.f;
            tmp[u] = __float2bfloat16(v);
        }
        *(uint4*)(Skb + (bh * 1152 + 1024 + jj) * 64 + dg0) = *(const uint4*)tmp;
    } else {
        // SvT cols [2080+1024, 2080+1056) of GTS rows bh*128+dd (dd<64), and
        // SvC cols [1024,1056): jc<3 -> sqrt3*Sm_v; else 0
        const long e = ((long)(blk - 2149) * 256 + t) * 8;   // < 131072
        const long bh = e >> 11, rem = e & 2047;
        const long dd = rem >> 5, jc0 = rem & 31;
        const long h = bh & 7;
        __align__(16) bf16 tmp[8];
#pragma unroll
        for (int u = 0; u < 8; u++) {
            const long jc = jc0 + u;
            float v = (jc < 3) ? SQRT3 * ldin(Smv, jc * 512 + h * 64 + dd, f) : 0.f;
            tmp[u] = __float2bfloat16(v);
        }
        *(uint4*)(GTS + (bh * 128 + dd) * 3136 + 3104 + jc0) = *(const uint4*)tmp;
        *(uint4*)(SvC + (bh * 64 + dd) * 1056 + 1024 + jc0)  = *(const uint4*)tmp;
    }
}

#define TM 128
#define BK 32

// MFMA NT GEMM (m97 structure), TNV = 128 or 64 (N tile width; TNV=64 doubles grid.x
// for occupancy on small/latency-bound shapes).
// OMODE 2: GT transposed scatter into GTS: dst row=(c>>6)*128+(c&63), col=rg; skip rg>=zeroN
// OMODE 3: qkv scatter: c<512 -> Cv (qb, ldc); 512<=c<1024 -> Cv2=Skb; c>=1024 ->
//          Cv3=GTS SvT region (transposed uint2) + Cv4=SvC
// OMODE 4: Ck scatter into Cv=kb: col c -> head c>>6, dg c&63; row rg -> b=rg>>11,j=rg&2047
// OMODE 5: A staged in regs from two f32 matrices (A=out0, Cv2=out1), f32 out (+bias)
template<int OMODE, int TNV>
__global__ __launch_bounds__(256)
void gemm_nt(const bf16* __restrict__ A, long lda, long sAz,
             const bf16* __restrict__ B, long ldb, long sBz,
             void* __restrict__ Cv, long ldc, long sCz,
             int K,
             const bf16* __restrict__ bias,
             int validN, int zeroN,
             void* __restrict__ Cv2, void* __restrict__ Cv3, void* __restrict__ Cv4)
{
    constexpr int NJ = TNV / 32;     // col sub-tiles per wave (4 or 2)
    __shared__ __align__(16) short As[TM * BK];
    __shared__ __align__(16) short Bs[TNV * BK];

    const int t = threadIdx.x;
    const int wave = t >> 6;
    const int lane = t & 63;
    const int bn = blockIdx.x, bm = blockIdx.y, z = blockIdx.z;

    const bf16* Ab = A + (long)z * sAz + (long)bm * TM * lda;
    const bf16* Bb = B + (long)z * sBz + (long)bn * TNV * ldb;

    const int lrow = t >> 2;          // 0..63
    const int lcol = (t & 3) << 3;    // 0,8,16,24

    const f32x4 vzero = {0.f, 0.f, 0.f, 0.f};
    f32x4 acc[4][NJ];
#pragma unroll
    for (int i = 0; i < 4; i++)
#pragma unroll
        for (int j = 0; j < NJ; j++) acc[i][j] = vzero;

    const int wr = (wave >> 1) << 6;  // 0/64
    const int wc = (wave & 1) * (TNV / 2);   // 0/64 or 0/32
    const int fr = lane & 15;
    const int fq = (lane >> 4) << 3;

    for (int k0 = 0; k0 < K; k0 += BK) {
        __syncthreads();  // prev iter's ds_reads done before LDS overwrite
        if constexpr (OMODE == 5) {
            // A tile = bf16(out0 + out1), staged via registers
            const int ar = t >> 1;
            const int ac = (t & 1) << 4;
            const float* a0 = (const float*)A   + (long)(bm * TM + ar) * lda + k0 + ac;
            const float* a1 = (const float*)Cv2 + (long)(bm * TM + ar) * lda + k0 + ac;
            __align__(16) bf16 tt[16];
#pragma unroll
            for (int u = 0; u < 4; u++) {
                const float4 v0 = *(const float4*)(a0 + u * 4);
                const float4 v1 = *(const float4*)(a1 + u * 4);
                tt[u * 4 + 0] = __float2bfloat16(v0.x + v1.x);
                tt[u * 4 + 1] = __float2bfloat16(v0.y + v1.y);
                tt[u * 4 + 2] = __float2bfloat16(v0.z + v1.z);
                tt[u * 4 + 3] = __float2bfloat16(v0.w + v1.w);
            }
            *(uint4*)&As[ar * BK + ac]     = *(const uint4*)&tt[0];
            *(uint4*)&As[ar * BK + ac + 8] = *(const uint4*)&tt[8];
        } else {
            gld_lds16(Ab + (long)lrow * lda + (k0 + lcol),        (char*)As + wave * 1024);
            gld_lds16(Ab + (long)(64 + lrow) * lda + (k0 + lcol), (char*)As + 4096 + wave * 1024);
        }
        gld_lds16(Bb + (long)lrow * ldb + (k0 + lcol),        (char*)Bs + wave * 1024);
        if constexpr (TNV == 128)
            gld_lds16(Bb + (long)(64 + lrow) * ldb + (k0 + lcol), (char*)Bs + 4096 + wave * 1024);
        __builtin_amdgcn_s_waitcnt(0);   // drain vmcnt before barrier
        __syncthreads();

        frag_t af[4], bfr[NJ];
#pragma unroll
        for (int i = 0; i < 4; i++) af[i]  = *(const frag_t*)&As[(wr + i * 16 + fr) * BK + fq];
#pragma unroll
        for (int j = 0; j < NJ; j++) bfr[j] = *(const frag_t*)&Bs[(wc + j * 16 + fr) * BK + fq];
#pragma unroll
        for (int i = 0; i < 4; i++)
#pragma unroll
            for (int j = 0; j < NJ; j++)
                acc[i][j] = mfma_16x16x32<frag_t>(af[i], bfr[j], acc[i][j]);
    }

    // epilogue: C/D layout col=lane&15, row=(lane>>4)*4+reg (m89/m91 verified)
    const int r0 = bm * TM + wr + ((lane >> 4) << 2);
    const int c0 = bn * TNV + wc + fr;

    if constexpr (OMODE == 2) {
#pragma unroll
        for (int j = 0; j < NJ; j++) {
            const int c = c0 + j * 16;
            bf16* rowp = (bf16*)Cv + ((long)(c >> 6) * 128 + (c & 63)) * 3136;
#pragma unroll
            for (int i = 0; i < 4; i++) {
                const int rgb = r0 + i * 16;      // multiple of 4
                if (rgb >= zeroN) continue;
                __align__(8) bf16 t4[4];
#pragma unroll
                for (int r = 0; r < 4; r++) t4[r] = __float2bfloat16(acc[i][j][r]);
                *(uint2*)(rowp + rgb) = *(const uint2*)t4;
            }
        }
        return;
    }
    if constexpr (OMODE == 3) {
        const int bb = bm >> 3;   // 1024 rows/batch, 128 rows/bm
#pragma unroll
        for (int j = 0; j < NJ; j++) {
            const int c = c0 + j * 16;
            const float bv = __bfloat162float(bias[c]);
            if (c < 512) {
#pragma unroll
                for (int i = 0; i < 4; i++)
#pragma unroll
                    for (int r = 0; r < 4; r++) {
                        const long rg = r0 + i * 16 + r;
                        ((bf16*)Cv)[rg * ldc + c] = __float2bfloat16(acc[i][j][r] + bv);
                    }
            } else if (c < 1024) {
                const int h = (c - 512) >> 6, dg = c & 63;
                bf16* base = (bf16*)Cv2 + ((long)(bb * 8 + h) * 1152) * 64 + dg;
#pragma unroll
                for (int i = 0; i < 4; i++)
#pragma unroll
                    for (int r = 0; r < 4; r++) {
                        const long jj = (r0 + i * 16 + r) & 1023;
                        base[jj * 64] = __float2bfloat16(acc[i][j][r] + bv);
                    }
            } else {
                const int h = (c - 1024) >> 6, dd = c & 63;
                bf16* svt = (bf16*)Cv3 + ((long)(bb * 8 + h) * 128 + dd) * 3136 + 2080;
                bf16* svc = (bf16*)Cv4 + ((long)(bb * 8 + h) * 64 + dd) * 1056;
#pragma unroll
                for (int i = 0; i < 4; i++) {
                    const long j0 = (r0 + i * 16) & 1023;
                    __align__(8) bf16 t4[4];
#pragma unroll
                    for (int r = 0; r < 4; r++) t4[r] = __float2bfloat16(acc[i][j][r] + bv);
                    *(uint2*)(svt + j0) = *(const uint2*)t4;
                    *(uint2*)(svc + j0) = *(const uint2*)t4;
                }
            }
        }
        return;
    }
    if constexpr (OMODE == 4) {
        const int bb = bm >> 4;   // 2048 rows/batch, 128 rows/bm
#pragma unroll
        for (int j = 0; j < NJ; j++) {
            const int c = c0 + j * 16;
            const float bv = __bfloat162float(bias[c]);
            const int h = c >> 6, dg = c & 63;
            bf16* base = (bf16*)Cv + ((long)(bb * 8 + h) * 2176) * 64 + dg;
#pragma unroll
            for (int i = 0; i < 4; i++)
#pragma unroll
                for (int r = 0; r < 4; r++) {
                    const long jj = (r0 + i * 16 + r) & 2047;
                    base[jj * 64] = __float2bfloat16(acc[i][j][r] + bv);
                }
        }
        return;
    }
    // OMODE 5: f32 out + bias
#pragma unroll
    for (int j = 0; j < NJ; j++) {
        const int c = c0 + j * 16;
        if (c >= zeroN) continue;
        const float bv = bias ? __bfloat162float(bias[c]) : 0.f;
#pragma unroll
        for (int i = 0; i < 4; i++)
#pragma unroll
            for (int r = 0; r < 4; r++) {
                const long rg = r0 + i * 16 + r;
                ((float*)Cv)[(long)z * sCz + rg * ldc + c] = acc[i][j][r] + bv;
            }
    }
}

// ---------------------------------------------------------------------------
// Fused flash attention, PHASE-SPLIT grid. SWAPPED QK (mfma(K,Q)): C rows = k,
// cols = q -> each lane owns one q-row with adjacent-k regs. P~ = exp2 (no max;
// logits pre-scaled 0.125*log2e), packed to bf16 pairs in-register, staged via
// a tiny XOR-swizzled packed LDS buffer (4 b64 writes + 2 b128 reads per it).
// kf/gf LDS reads hoisted across both it-tiles. Row-sums via MFMA vs ones.
// LDS exactly 40 KiB -> 4 blocks/CU; grid 1024 fully resident.
// ---------------------------------------------------------------------------
__global__ __launch_bounds__(256, 4)
void attn_fused(const bf16* __restrict__ q,    // [8192][512] (prescaled 0.125*log2e)
                const bf16* __restrict__ kb,   // [64][2176][64]
                const bf16* __restrict__ Skb,  // [64][1152][64]
                const bf16* __restrict__ GTS,  // [64][128][3136]
                float* __restrict__ out0,      // [8192][512] f32 phase0 partial
                float* __restrict__ out1)      // [8192][512] f32 phase1 partial
{
    __shared__ __align__(16) bf16 Ks[2][64 * 64];     // 16 KB (Q staged here at init)
    __shared__ __align__(16) bf16 Gs[2][64 * 64];     // 16 KB
    __shared__ __align__(16) unsigned Psw[4][16][32]; // 8 KB packed P~ (swizzled)

    const int t = threadIdx.x;
    const int w = t >> 6, lane = t & 63;
    const int bh = blockIdx.x, bm = blockIdx.y;
    const int phase = blockIdx.z;
    const int b = bh >> 3, h = bh & 7;
    const int g  = lane >> 4;        // 0..3
    const int fr = lane & 15;

    // stage Q[128][64] linear into Ks region, read qf frags once
    const bf16* Qg = q + ((long)(b * 1024 + bm * 128)) * 512 + h * 64;
    {
        const int qr = t >> 3, qc0 = (t & 7) << 3;
#pragma unroll
        for (int u = 0; u < 4; u++)
            gld_lds16(Qg + (long)(u * 32 + qr) * 512 + qc0, (char*)Ks + u * 4096 + w * 1024);
    }
    __builtin_amdgcn_s_waitcnt(0);
    __syncthreads();

    frag_t qf[2][2];
#pragma unroll
    for (int it = 0; it < 2; it++)
#pragma unroll
        for (int kh = 0; kh < 2; kh++)
            qf[it][kh] = *(const frag_t*)&((const bf16*)Ks)[(w * 32 + it * 16 + fr) * 64 + kh * 32 + g * 8];
    __syncthreads();   // all qf reads done before Ks restage

    // all-ones bf16 B-fragment for row-sum MFMA
    union { frag_t f; short s[8]; } ou;
#pragma unroll
    for (int i = 0; i < 8; i++) ou.s[i] = 0x3F80;
    const frag_t onesf = ou.f;

    const f32x4 vzero = {0.f, 0.f, 0.f, 0.f};
    const int rs = t >> 3, gs = t & 7;              // stage: row, phys group
    const int glo = gs ^ (rs & 7);                  // logical group (involution)

    const bf16* Kb = phase ? Skb + (long)bh * 1152 * 64 : kb + (long)bh * 2176 * 64;
    const bf16* Gb = GTS + (long)bh * 128 * 3136 + (phase ? 2080 : 0);
    const int NC = phase ? 17 : 33;
    const int valid = phase ? 1027 : 2051;

    f32x4 oacc[2][4];
    f32x4 lacc[2];
#pragma unroll
    for (int it = 0; it < 2; it++) {
        lacc[it] = vzero;
#pragma unroll
        for (int dt = 0; dt < 4; dt++) oacc[it][dt] = vzero;
    }

    // prologue: stage chunk 0 into buffer 0
    gld_lds16(Kb + (long)rs * 64 + glo * 8,          (char*)Ks[0] + w * 1024);
    gld_lds16(Kb + (long)(32 + rs) * 64 + glo * 8,   (char*)Ks[0] + 4096 + w * 1024);
    gld_lds16(Gb + (long)rs * 3136 + glo * 8,        (char*)Gs[0] + w * 1024);
    gld_lds16(Gb + (long)(32 + rs) * 3136 + glo * 8, (char*)Gs[0] + 4096 + w * 1024);

    unsigned* prow = &Psw[w][fr][0];
    const int swzk = (fr & 7) << 2;

    for (int c = 0; c < NC; c++) {
        const int buf = c & 1;
        __builtin_amdgcn_s_waitcnt(0);   // my stage for chunk c done
        __syncthreads();                  // everyone's done; prev-buf reads done
        if (c + 1 < NC) {                 // prefetch next chunk (hidden under compute)
            const bf16* Kc = Kb + (long)(c + 1) * 64 * 64;
            const bf16* Gc = Gb + (c + 1) * 64;
            gld_lds16(Kc + (long)rs * 64 + glo * 8,          (char*)Ks[buf ^ 1] + w * 1024);
            gld_lds16(Kc + (long)(32 + rs) * 64 + glo * 8,   (char*)Ks[buf ^ 1] + 4096 + w * 1024);
            gld_lds16(Gc + (long)rs * 3136 + glo * 8,        (char*)Gs[buf ^ 1] + w * 1024);
            gld_lds16(Gc + (long)(32 + rs) * 3136 + glo * 8, (char*)Gs[buf ^ 1] + 4096 + w * 1024);
        }
        const bf16* Kl = Ks[buf];
        const bf16* Gl = Gs[buf];

        // QK^T swapped: s2[it][ct], C rows = k (ct*16+4g+r), cols = q (fr)
        f32x4 s2[2][4];
#pragma unroll
        for (int it = 0; it < 2; it++)
#pragma unroll
            for (int ct = 0; ct < 4; ct++) s2[it][ct] = vzero;
        __builtin_amdgcn_s_setprio(1);
#pragma unroll
        for (int ct = 0; ct < 4; ct++)
#pragma unroll
            for (int kh = 0; kh < 2; kh++) {
                const int gph = (kh * 4 + g) ^ (fr & 7);
                const frag_t kf = *(const frag_t*)&Kl[(ct * 16 + fr) * 64 + gph * 8];
                s2[0][ct] = mfma_16x16x32<frag_t>(kf, qf[0][kh], s2[0][ct]);
                s2[1][ct] = mfma_16x16x32<frag_t>(kf, qf[1][kh], s2[1][ct]);
            }
        __builtin_amdgcn_s_setprio(0);

        if (c == NC - 1) {   // mask padded k rows (only last chunk has any)
#pragma unroll
            for (int ct = 0; ct < 4; ct++)
#pragma unroll
                for (int r = 0; r < 4; r++) {
                    const int kAbs = c * 64 + ct * 16 + 4 * g + r;
                    if (kAbs >= valid) { s2[0][ct][r] = -1.0e30f; s2[1][ct][r] = -1.0e30f; }
                }
        }

        // per it-tile: exp2, pack pairs, swizzled b64 store, b128 read of A-frags
        frag_t pa[2][2];
#pragma unroll
        for (int it = 0; it < 2; it++) {
#pragma unroll
            for (int ct = 0; ct < 4; ct++) {
                const unsigned w0 = pack2(exp2f(s2[it][ct][0]), exp2f(s2[it][ct][1]));
                const unsigned w1 = pack2(exp2f(s2[it][ct][2]), exp2f(s2[it][ct][3]));
                *(uint2*)&prow[(ct * 8 + 2 * g) ^ swzk] = make_uint2(w0, w1);
            }
#pragma unroll
            for (int kh = 0; kh < 2; kh++)
                pa[it][kh] = *(const frag_t*)&prow[(kh * 16 + 4 * g) ^ swzk];
        }

        // PV + row-sum: A = P~ (q-rows lane-local), B = G^T rows / ones
        __builtin_amdgcn_s_setprio(1);
#pragma unroll
        for (int kh = 0; kh < 2; kh++) {
            lacc[0] = mfma_16x16x32<frag_t>(pa[0][kh], onesf, lacc[0]);
            lacc[1] = mfma_16x16x32<frag_t>(pa[1][kh], onesf, lacc[1]);
#pragma unroll
            for (int dt = 0; dt < 4; dt++) {
                const int gph = (kh * 4 + g) ^ (fr & 7);
                const frag_t gf = *(const frag_t*)&Gl[(dt * 16 + fr) * 64 + gph * 8];
                oacc[0][dt] = mfma_16x16x32<frag_t>(pa[0][kh], gf, oacc[0][dt]);
                oacc[1][dt] = mfma_16x16x32<frag_t>(pa[1][kh], gf, oacc[1][dt]);
            }
        }
        __builtin_amdgcn_s_setprio(0);
    }

    // epilogue: out = oacc / l (+ G bias col for phase 0), f32 partial store
    float gba[4] = {0.f, 0.f, 0.f, 0.f};
    if (phase == 0) {
        const bf16* gp = GTS + (long)bh * 128 * 3136 + 2051;
#pragma unroll
        for (int dt = 0; dt < 4; dt++)
            gba[dt] = __bfloat162float(gp[(long)(dt * 16 + fr) * 3136]);
    }
    float* Og = (phase ? out1 : out0) + ((long)(b * 1024 + bm * 128)) * 512 + h * 64;
#pragma unroll
    for (int it = 0; it < 2; it++)
#pragma unroll
        for (int r = 0; r < 4; r++) {
            const float inv = 1.f / lacc[it][r];
#pragma unroll
            for (int dt = 0; dt < 4; dt++) {
                Og[(long)(w * 32 + it * 16 + g * 4 + r) * 512 + dt * 16 + fr] =
                    oacc[it][dt][r] * inv + gba[dt];
            }
        }
}

extern "C" void kernel_launch(void* const* d_in, const int* in_sizes, int n_in,
                              void* d_out, int out_size, void* d_ws, size_t ws_size,
                              hipStream_t stream)
{
    const void* inp  = d_in[0];
    const void* x    = d_in[1];
    const void* y    = d_in[2];
    const void* Wq   = d_in[3];
    const void* bq   = d_in[4];
    const void* Wkv  = d_in[5];
    const void* bkv  = d_in[6];
    const void* Wf   = d_in[7];
    const void* bff  = d_in[8];
    const void* Wo   = d_in[9];
    const void* bo   = d_in[10];
    const void* m_k  = d_in[11];
    // d_in[12] = m_v : dead code (v never used by the reference)
    const void* Sm_k = d_in[13];
    const void* Sm_v = d_in[14];

    char* ws = (char*)d_ws;
    int*  flag = (int*)(ws + 0);
    bf16* WqB  = (bf16*)(ws + 256);        // [512][512]  (pre-scaled 0.125*log2e)
    bf16* WkvB = (bf16*)(ws + 524544);     // [1024][512] (contiguous -> [1536][512])
    bf16* WoB  = (bf16*)(ws + 1573120);    // [512][512]
    bf16* WfT  = (bf16*)(ws + 2097408);    // [2176][1056] Wf^T (+bf row 2051)
    bf16* bqB  = (bf16*)(ws + 6693120);    // [512] (pre-scaled; contiguous with bkvB)
    bf16* bkvB = (bf16*)(ws + 6694144);    // [1024]
    bf16* boB  = (bf16*)(ws + 6696192);    // [512]
    bf16* qb   = (bf16*)(ws + 6706432);    // [8192][512]
    bf16* kb   = (bf16*)(ws + 15095040);   // [64][2176][64]
    bf16* Skb  = (bf16*)(ws + 32920832);   // [64][1152][64]
    bf16* GTS  = (bf16*)(ws + 42358016);   // [64][128][3136]: [0,2080)=G^T, [2080,3136)=Sv^T
    char* OV   = ws + 93738240;

    // overlay lifetimes (stream order):
    //   inpB [8192][512] bf16 @OV           : dies after qkv gemm
    //   SvC  [4096][1056] bf16 @OV+16777216 : dies after GT gemm
    //   ctxB [16384][512] bf16 @OV+33554432 : own region (written early by cvt_in)
    //   out0f/out1f [8192][512] f32 @OV / @OV+16777216 : attn outputs
    bf16*  inpB  = (bf16*)(OV);
    bf16*  SvC   = (bf16*)(OV + 16777216);
    bf16*  ctxB  = (bf16*)(OV + 33554432);
    float* out0f = (float*)(OV);
    float* out1f = (float*)(OV + 16777216);
    // total ws need: 93,738,240 + 33,554,432 + 16,777,216 = 144,069,888 (proven available)

    const dim3 blk(256);
    const bf16* nulb = nullptr;
    const float QS = 0.125f * 1.44269504f;   // fold softmax scale * log2(e) into q

    detect_dtype<<<dim3(1), dim3(64), 0, stream>>>(inp, flag);

    // ONE prep kernel: weights + WfT + biases + token/zero prefill of kb/Skb/SvT/SvC
    prep<<<dim3(2213), blk, 0, stream>>>(Wq, Wkv, Wo, Wf, bff, bq, bkv, bo,
                                         m_k, Sm_k, Sm_v,
                                         WqB, WkvB, WoB, WfT, bqB, bkvB, boB,
                                         kb, Skb, GTS, SvC, flag, QS);

    // inpB <- inp, ctxB <- concat(x,y)  (one kernel; ctxB has its own region now)
    cvt_in<<<dim3(6144), blk, 0, stream>>>(inp, x, y, inpB, ctxB, flag);

    // merged qkv GEMM with fused scatter (TN=128, 768 blocks = 3/CU):
    //   cols [0,512)    -> qb (pre-scaled q)
    //   cols [512,1024) -> Skb[bh][j][dg]
    //   cols [1024,1536)-> GTS SvT region + SvC
    gemm_nt<3, 128><<<dim3(12, 64, 1), blk, 0, stream>>>(inpB, 512, 0, WqB, 512, 0,
        (void*)qb, 512, 0, 512, bqB, 1536, 1536, (void*)Skb, (void*)GTS, (void*)SvC);

    // G = WfT[2176][1056] @ SvC[4096][1056]^T -> GTS G-region
    // TN=64: grid (64,17) = 1088 blocks = 4.25/CU (was 544 = 2.1/CU)
    gemm_nt<2, 64><<<dim3(64, 17, 1), blk, 0, stream>>>(WfT, 1056, 0, SvC, 1056, 0,
        (void*)GTS, 0, 0, 1056, nulb, 0, 2080, nullptr, nullptr, nullptr);

    // Ck GEMM with fused kb scatter. TN=64: grid (8,128) = 1024 blocks = 4/CU
    gemm_nt<4, 64><<<dim3(8, 128, 1), blk, 0, stream>>>(ctxB, 512, 0, WkvB, 512, 0,
        (void*)kb, 0, 0, 512, bkvB, 512, 512, nullptr, nullptr, nullptr);

    // fused attention, phase-split grid (1024 blocks, 4 blocks/CU): f32 partials
    attn_fused<<<dim3(64, 8, 2), blk, 0, stream>>>(qb, kb, Skb, GTS, out0f, out1f);

    // final = bf16(out0f+out1f) @ Wo^T + bo -> d_out (f32); A staged from the two
    // f32 partials in-kernel. TN=64: grid (8,64) = 512 blocks = 2/CU (was 1/CU)
    gemm_nt<5, 64><<<dim3(8, 64, 1), blk, 0, stream>>>((const bf16*)out0f, 512, 0, WoB, 512, 0,
        d_out, 512, 0, 512, boB, 512, 512, (void*)out1f, nullptr, nullptr);
}

// Round 9
// 360.883 us; speedup vs baseline: 1.0609x; 1.0609x over previous
//
#include <hip/hip_runtime.h>
#include <hip/hip_bf16.h>
#include <type_traits>

using bf16 = __hip_bfloat16;
typedef float f32x4 __attribute__((ext_vector_type(4)));
typedef __bf16 bf16x8_t __attribute__((ext_vector_type(8)));
typedef short  s16x8_t  __attribute__((ext_vector_type(8)));

template <typename V, typename = void> struct MfmaWorks : std::false_type {};
template <typename V>
struct MfmaWorks<V, std::void_t<decltype(__builtin_amdgcn_mfma_f32_16x16x32_bf16(
    std::declval<V>(), std::declval<V>(), std::declval<f32x4>(), 0, 0, 0))>> : std::true_type {};
using frag_t = std::conditional_t<MfmaWorks<bf16x8_t>::value, bf16x8_t, s16x8_t>;

template <typename V>
__device__ __forceinline__ f32x4 mfma_16x16x32(V a, V b, f32x4 c) {
    return __builtin_amdgcn_mfma_f32_16x16x32_bf16(a, b, c, 0, 0, 0);
}

__device__ __forceinline__ void gld_lds16(const void* g, void* l) {
    __builtin_amdgcn_global_load_lds(
        (const __attribute__((address_space(1))) unsigned int*)g,
        (__attribute__((address_space(3))) unsigned int*)l, 16, 0, 0);
}

// pack two f32 -> u32 of 2 bf16 (lo first); compiler fuses to v_cvt_pk_bf16_f32
__device__ __forceinline__ unsigned pack2(float lo, float hi) {
    bf16 a = __float2bfloat16(lo), b = __float2bfloat16(hi);
    unsigned short al, bl;
    __builtin_memcpy(&al, &a, 2);
    __builtin_memcpy(&bl, &b, 2);
    return (unsigned)al | ((unsigned)bl << 16);
}

// ---------- runtime-dtype input loader: flag==1 -> f32, flag==0 -> bf16 ----------
__device__ __forceinline__ float ldin(const void* p, long i, int f32) {
    return f32 ? ((const float*)p)[i] : __bfloat162float(((const bf16*)p)[i]);
}

// Inline dtype probe (identical 512-sample set as the old detect_dtype kernel):
// wave 0 samples inp bf16 at even indices 0..510; >128/256 sane -> bf16 (0), else f32 (1).
__device__ __forceinline__ int detect_f32(const void* __restrict__ inp) {
    __shared__ int sflag;
    const int t = threadIdx.x;
    if (t < 64) {
        int cnt = 0;
#pragma unroll
        for (int s = 0; s < 4; s++) {
            float v = __bfloat162float(((const bf16*)inp)[2 * (t + 64 * s)]);
            float a = fabsf(v);
            bool sane = (a == 0.f) || (a > 9e-4f && a < 1000.f);
            unsigned long long m = __ballot(sane);
            cnt += (int)__popcll(m);
        }
        if (t == 0) sflag = (cnt > 128) ? 0 : 1;
    }
    __syncthreads();
    return sflag;
}

// ---------------------------------------------------------------------------
// ONE prep kernel: input conversions (inpB, ctxB) + all weight/bias conversions
// + WfT build + memory-token / zero prefill of kb, Skb, GTS-SvT, SvC.
// blocks: [0,2048) inpB | [2048,6144) ctxB | [6144,6656) weights |
//         [6656,7778) WfT | [7778,7781) biases | [7781,8037) kb tail |
//         [8037,8293) Skb tail | [8293,8357) SvT+SvC tail
// ---------------------------------------------------------------------------
__global__ __launch_bounds__(256)
void prep_all(const void* __restrict__ inp, const void* __restrict__ x,
              const void* __restrict__ y,
              const void* __restrict__ Wq, const void* __restrict__ Wkv,
              const void* __restrict__ Wo, const void* __restrict__ Wf,
              const void* __restrict__ bff, const void* __restrict__ bq,
              const void* __restrict__ bkv, const void* __restrict__ bo,
              const void* __restrict__ mk, const void* __restrict__ Smk,
              const void* __restrict__ Smv,
              bf16* __restrict__ inpB, bf16* __restrict__ ctxB,
              bf16* __restrict__ WqB, bf16* __restrict__ WkvB, bf16* __restrict__ WoB,
              bf16* __restrict__ WfT, bf16* __restrict__ bqB, bf16* __restrict__ bkvB,
              bf16* __restrict__ boB, bf16* __restrict__ kb, bf16* __restrict__ Skb,
              bf16* __restrict__ GTS, bf16* __restrict__ SvC, float qscale)
{
    const int f = detect_f32(inp);
    const int blk = blockIdx.x;
    const int t = threadIdx.x;
    const float SQRT3 = 1.7320508f;

    if (blk < 2048) {
        const long i0 = ((long)blk * 256 + t) * 8;   // < 4,194,304
#pragma unroll
        for (int u = 0; u < 8; u++)
            inpB[i0 + u] = __float2bfloat16(ldin(inp, i0 + u, f));
    } else if (blk < 6144) {
        const long i0 = ((long)(blk - 2048) * 256 + t) * 8;  // < 8,388,608
        const long r = i0 >> 9, c0 = i0 & 511;
        const long b = r >> 11, jj = r & 2047;
        const void* src = (jj < 1024) ? x : y;
        const long  soff = (jj < 1024) ? ((b * 1024 + jj) * 512 + c0)
                                       : ((b * 1024 + (jj - 1024)) * 512 + c0);
#pragma unroll
        for (int u = 0; u < 8; u++)
            ctxB[i0 + u] = __float2bfloat16(ldin(src, soff + u, f));
    } else if (blk < 6656) {
        const int wb = blk - 6144;
        long id = (long)wb * 256 + t;
        const void* src; bf16* dst; float sc;
        if (wb < 128)      { src = Wq;  dst = WqB;  sc = qscale; }
        else if (wb < 384) { src = Wkv; dst = WkvB; sc = 1.f; id -= 128L * 256; }
        else               { src = Wo;  dst = WoB;  sc = 1.f; id -= 384L * 256; }
        const long i0 = id * 8;
#pragma unroll
        for (int u = 0; u < 8; u++)
            dst[i0 + u] = __float2bfloat16(sc * ldin(src, i0 + u, f));
    } else if (blk < 7778) {
        // WfT[2176][1056]: WfT[j][r] = (j<2051 && r<1027) ? Wf[r][j]
        //                 : (j==2051 && r<1027) ? bf[r] : 0   (bias ones-row trick)
        const long i0 = ((long)(blk - 6656) * 256 + t) * 8;  // < 2,297,856
        if (i0 >= 2176L * 1056) return;
        const long j = i0 / 1056, r0 = i0 % 1056;
        __align__(16) bf16 tmp[8];
#pragma unroll
        for (int u = 0; u < 8; u++) {
            const long r = r0 + u;
            float v = 0.f;
            if (r < 1027) {
                if (j < 2051)       v = ldin(Wf, r * 2051 + j, f);
                else if (j == 2051) v = ldin(bff, r, f);
            }
            tmp[u] = __float2bfloat16(v);
        }
        *(uint4*)(WfT + i0) = *(const uint4*)tmp;
    } else if (blk < 7781) {
        const void* src; bf16* dst; int n; float sc;
        switch (blk - 7778) {
            case 0:  src = bq;  dst = bqB;  n = 512;  sc = qscale; break;
            case 1:  src = bkv; dst = bkvB; n = 1024; sc = 1.f;    break;
            default: src = bo;  dst = boB;  n = 512;  sc = 1.f;    break;
        }
        for (int i = t; i < n; i += 256)
            dst[i] = __float2bfloat16(sc * ldin(src, i, f));
    } else if (blk < 8037) {
        // kb[bh][2048+jj][dg]: jj<3 -> 8*m_k; else 0
        const long e = ((long)(blk - 7781) * 256 + t) * 8;   // < 524288
        const long bh = e >> 13, rem = e & 8191;
        const long jj = rem >> 6, dg0 = rem & 63;
        const long h = bh & 7;
        __align__(16) bf16 tmp[8];
#pragma unroll
        for (int u = 0; u < 8; u++) {
            float v = (jj < 3) ? 8.f * ldin(mk, jj * 512 + h * 64 + dg0 + u, f) : 0.f;
            tmp[u] = __float2bfloat16(v);
        }
        *(uint4*)(kb + (bh * 2176 + 2048 + jj) * 64 + dg0) = *(const uint4*)tmp;
    } else if (blk < 8293) {
        // Skb[bh][1024+jj][dg]: jj<3 -> 8*Sm_k; else 0
        const long e = ((long)(blk - 8037) * 256 + t) * 8;   // < 524288
        const long bh = e >> 13, rem = e & 8191;
        const long jj = rem >> 6, dg0 = rem & 63;
        const long h = bh & 7;
        __align__(16) bf16 tmp[8];
#pragma unroll
        for (int u = 0; u < 8; u++) {
            float v = (jj < 3) ? 8.f * ldin(Smk, jj * 512 + h * 64 + dg0 + u, f) : 0.f;
            tmp[u] = __float2bfloat16(v);
        }
        *(uint4*)(Skb + (bh * 1152 + 1024 + jj) * 64 + dg0) = *(const uint4*)tmp;
    } else {
        // SvT cols [2080+1024, 2080+1056) of GTS rows bh*128+dd (dd<64), and
        // SvC cols [1024,1056): jc<3 -> sqrt3*Sm_v; else 0
        const long e = ((long)(blk - 8293) * 256 + t) * 8;   // < 131072
        const long bh = e >> 11, rem = e & 2047;
        const long dd = rem >> 5, jc0 = rem & 31;
        const long h = bh & 7;
        __align__(16) bf16 tmp[8];
#pragma unroll
        for (int u = 0; u < 8; u++) {
            const long jc = jc0 + u;
            float v = (jc < 3) ? SQRT3 * ldin(Smv, jc * 512 + h * 64 + dd, f) : 0.f;
            tmp[u] = __float2bfloat16(v);
        }
        *(uint4*)(GTS + (bh * 128 + dd) * 3136 + 3104 + jc0) = *(const uint4*)tmp;
        *(uint4*)(SvC + (bh * 64 + dd) * 1056 + 1024 + jc0)  = *(const uint4*)tmp;
    }
}

#define BK 32

// ---------------------------------------------------------------------------
// qkv GEMM (TM=TN=128, K=512): [q | Skv | Sv] = inpB @ [Wq;Wkv]^T + [bq;bkv]
// with fused scatter: cols [0,512)->qb; [512,1024)->Skb; [1024,1536)->SvT+SvC.
// grid (12, 64).
// ---------------------------------------------------------------------------
__global__ __launch_bounds__(256)
void gemm_qkv(const bf16* __restrict__ A, const bf16* __restrict__ B,
              const bf16* __restrict__ bias,
              bf16* __restrict__ qb, bf16* __restrict__ Skb,
              bf16* __restrict__ GTS, bf16* __restrict__ SvC)
{
    __shared__ __align__(16) short As[128 * BK];
    __shared__ __align__(16) short Bs[128 * BK];

    const int t = threadIdx.x;
    const int wave = t >> 6, lane = t & 63;
    const int bn = blockIdx.x, bm = blockIdx.y;

    const bf16* Ab = A + (long)bm * 128 * 512;
    const bf16* Bb = B + (long)bn * 128 * 512;

    const int lrow = t >> 2, lcol = (t & 3) << 3;

    const f32x4 vzero = {0.f, 0.f, 0.f, 0.f};
    f32x4 acc[4][4];
#pragma unroll
    for (int i = 0; i < 4; i++)
#pragma unroll
        for (int j = 0; j < 4; j++) acc[i][j] = vzero;

    const int wr = (wave >> 1) << 6;
    const int wc = (wave & 1) << 6;
    const int fr = lane & 15;
    const int fq = (lane >> 4) << 3;

    for (int k0 = 0; k0 < 512; k0 += BK) {
        __syncthreads();
        gld_lds16(Ab + (long)lrow * 512 + (k0 + lcol),        (char*)As + wave * 1024);
        gld_lds16(Ab + (long)(64 + lrow) * 512 + (k0 + lcol), (char*)As + 4096 + wave * 1024);
        gld_lds16(Bb + (long)lrow * 512 + (k0 + lcol),        (char*)Bs + wave * 1024);
        gld_lds16(Bb + (long)(64 + lrow) * 512 + (k0 + lcol), (char*)Bs + 4096 + wave * 1024);
        __builtin_amdgcn_s_waitcnt(0);
        __syncthreads();

        frag_t af[4], bfr[4];
#pragma unroll
        for (int i = 0; i < 4; i++) af[i]  = *(const frag_t*)&As[(wr + i * 16 + fr) * BK + fq];
#pragma unroll
        for (int j = 0; j < 4; j++) bfr[j] = *(const frag_t*)&Bs[(wc + j * 16 + fr) * BK + fq];
#pragma unroll
        for (int i = 0; i < 4; i++)
#pragma unroll
            for (int j = 0; j < 4; j++)
                acc[i][j] = mfma_16x16x32<frag_t>(af[i], bfr[j], acc[i][j]);
    }

    const int r0 = bm * 128 + wr + ((lane >> 4) << 2);
    const int c0 = bn * 128 + wc + fr;
    const int bb = bm >> 3;   // 1024 rows/batch
#pragma unroll
    for (int j = 0; j < 4; j++) {
        const int c = c0 + j * 16;
        const float bv = __bfloat162float(bias[c]);
        if (c < 512) {
#pragma unroll
            for (int i = 0; i < 4; i++)
#pragma unroll
                for (int r = 0; r < 4; r++) {
                    const long rg = r0 + i * 16 + r;
                    qb[rg * 512 + c] = __float2bfloat16(acc[i][j][r] + bv);
                }
        } else if (c < 1024) {
            const int h = (c - 512) >> 6, dg = c & 63;
            bf16* base = Skb + ((long)(bb * 8 + h) * 1152) * 64 + dg;
#pragma unroll
            for (int i = 0; i < 4; i++)
#pragma unroll
                for (int r = 0; r < 4; r++) {
                    const long jj = (r0 + i * 16 + r) & 1023;
                    base[jj * 64] = __float2bfloat16(acc[i][j][r] + bv);
                }
        } else {
            const int h = (c - 1024) >> 6, dd = c & 63;
            bf16* svt = GTS + ((long)(bb * 8 + h) * 128 + dd) * 3136 + 2080;
            bf16* svc = SvC + ((long)(bb * 8 + h) * 64 + dd) * 1056;
#pragma unroll
            for (int i = 0; i < 4; i++) {
                const long j0 = (r0 + i * 16) & 1023;
                __align__(8) bf16 t4[4];
#pragma unroll
                for (int r = 0; r < 4; r++) t4[r] = __float2bfloat16(acc[i][j][r] + bv);
                *(uint2*)(svt + j0) = *(const uint2*)t4;
                *(uint2*)(svc + j0) = *(const uint2*)t4;
            }
        }
    }
}

// ---------------------------------------------------------------------------
// Merged GT + Ck dispatch (independent GEMMs packed into one grid of 1056):
//   blocks [0,544):  GT = WfT[2176][1056] @ SvC[4096][1056]^T, transposed
//                    scatter into GTS G-region (bn=id&31, bm=id>>5, K=1056)
//   blocks [544,1056): Ck = ctxB[16384][512] @ WkvB[512][512]^T + bkv,
//                    scattered into kb (bn=i&3, bm=i>>2, K=512)
// Both TM=TN=128 (A-panel read-multiplicity kept minimal; r8 showed TN=64
// doubles A traffic and regresses).
// ---------------------------------------------------------------------------
__global__ __launch_bounds__(256)
void gemm_gtck(const bf16* __restrict__ WfT, const bf16* __restrict__ SvC,
               bf16* __restrict__ GTS,
               const bf16* __restrict__ ctxB, const bf16* __restrict__ WkvB,
               const bf16* __restrict__ bkvB, bf16* __restrict__ kb)
{
    __shared__ __align__(16) short As[128 * BK];
    __shared__ __align__(16) short Bs[128 * BK];

    const int t = threadIdx.x;
    const int wave = t >> 6, lane = t & 63;
    const int id = blockIdx.x;
    const bool isGT = id < 544;

    int bn, bm, K;
    const bf16 *A, *B;
    long lda, ldb;
    if (isGT) { bn = id & 31; bm = id >> 5; A = WfT; lda = 1056; B = SvC; ldb = 1056; K = 1056; }
    else { const int i2 = id - 544; bn = i2 & 3; bm = i2 >> 2; A = ctxB; lda = 512; B = WkvB; ldb = 512; K = 512; }

    const bf16* Ab = A + (long)bm * 128 * lda;
    const bf16* Bb = B + (long)bn * 128 * ldb;

    const int lrow = t >> 2, lcol = (t & 3) << 3;

    const f32x4 vzero = {0.f, 0.f, 0.f, 0.f};
    f32x4 acc[4][4];
#pragma unroll
    for (int i = 0; i < 4; i++)
#pragma unroll
        for (int j = 0; j < 4; j++) acc[i][j] = vzero;

    const int wr = (wave >> 1) << 6;
    const int wc = (wave & 1) << 6;
    const int fr = lane & 15;
    const int fq = (lane >> 4) << 3;

    for (int k0 = 0; k0 < K; k0 += BK) {
        __syncthreads();
        gld_lds16(Ab + (long)lrow * lda + (k0 + lcol),        (char*)As + wave * 1024);
        gld_lds16(Ab + (long)(64 + lrow) * lda + (k0 + lcol), (char*)As + 4096 + wave * 1024);
        gld_lds16(Bb + (long)lrow * ldb + (k0 + lcol),        (char*)Bs + wave * 1024);
        gld_lds16(Bb + (long)(64 + lrow) * ldb + (k0 + lcol), (char*)Bs + 4096 + wave * 1024);
        __builtin_amdgcn_s_waitcnt(0);
        __syncthreads();

        frag_t af[4], bfr[4];
#pragma unroll
        for (int i = 0; i < 4; i++) af[i]  = *(const frag_t*)&As[(wr + i * 16 + fr) * BK + fq];
#pragma unroll
        for (int j = 0; j < 4; j++) bfr[j] = *(const frag_t*)&Bs[(wc + j * 16 + fr) * BK + fq];
#pragma unroll
        for (int i = 0; i < 4; i++)
#pragma unroll
            for (int j = 0; j < 4; j++)
                acc[i][j] = mfma_16x16x32<frag_t>(af[i], bfr[j], acc[i][j]);
    }

    const int r0 = bm * 128 + wr + ((lane >> 4) << 2);
    const int c0 = bn * 128 + wc + fr;

    if (isGT) {
        // transposed scatter: dst row = (c>>6)*128 + (c&63), col = rg; skip rg >= 2080
#pragma unroll
        for (int j = 0; j < 4; j++) {
            const int c = c0 + j * 16;
            bf16* rowp = GTS + ((long)(c >> 6) * 128 + (c & 63)) * 3136;
#pragma unroll
            for (int i = 0; i < 4; i++) {
                const int rgb = r0 + i * 16;      // multiple of 4
                if (rgb >= 2080) continue;
                __align__(8) bf16 t4[4];
#pragma unroll
                for (int r = 0; r < 4; r++) t4[r] = __float2bfloat16(acc[i][j][r]);
                *(uint2*)(rowp + rgb) = *(const uint2*)t4;
            }
        }
    } else {
        const int bb = bm >> 4;   // 2048 rows/batch
#pragma unroll
        for (int j = 0; j < 4; j++) {
            const int c = c0 + j * 16;
            const float bv = __bfloat162float(bkvB[c]);
            const int h = c >> 6, dg = c & 63;
            bf16* base = kb + ((long)(bb * 8 + h) * 2176) * 64 + dg;
#pragma unroll
            for (int i = 0; i < 4; i++)
#pragma unroll
                for (int r = 0; r < 4; r++) {
                    const long jj = (r0 + i * 16 + r) & 2047;
                    base[jj * 64] = __float2bfloat16(acc[i][j][r] + bv);
                }
        }
    }
}

// ---------------------------------------------------------------------------
// Final GEMM, TM=64 x TN=128 (grid (4,128) = 512 blocks = 2/CU; grid.x stays 4
// so the f32 A partials are read+converted only 4x — the r8 TN=64 mistake
// doubled that). A tile = bf16(out0+out1) staged via registers.
// ---------------------------------------------------------------------------
__global__ __launch_bounds__(256)
void gemm_final64(const float* __restrict__ o0, const float* __restrict__ o1,
                  const bf16* __restrict__ B, const bf16* __restrict__ bias,
                  float* __restrict__ out)
{
    __shared__ __align__(16) short As[64 * BK];    // 4 KB
    __shared__ __align__(16) short Bs[128 * BK];   // 8 KB

    const int t = threadIdx.x;
    const int wave = t >> 6, lane = t & 63;
    const int bn = blockIdx.x, bm = blockIdx.y;

    const bf16* Bb = B + (long)bn * 128 * 512;
    const int lrow = t >> 2, lcol = (t & 3) << 3;

    const f32x4 vzero = {0.f, 0.f, 0.f, 0.f};
    f32x4 acc[2][4];
#pragma unroll
    for (int i = 0; i < 2; i++)
#pragma unroll
        for (int j = 0; j < 4; j++) acc[i][j] = vzero;

    const int wr = (wave >> 1) << 5;   // 0/32
    const int wc = (wave & 1) << 6;    // 0/64
    const int fr = lane & 15;
    const int fq = (lane >> 4) << 3;

    for (int k0 = 0; k0 < 512; k0 += BK) {
        __syncthreads();
        {   // A stage: 64 rows x 32 cols, bf16(o0+o1)
            const int ar = t >> 2, ac = (t & 3) << 3;
            const float* a0 = o0 + (long)(bm * 64 + ar) * 512 + k0 + ac;
            const float* a1 = o1 + (long)(bm * 64 + ar) * 512 + k0 + ac;
            __align__(16) bf16 tt[8];
#pragma unroll
            for (int u = 0; u < 2; u++) {
                const float4 v0 = *(const float4*)(a0 + u * 4);
                const float4 v1 = *(const float4*)(a1 + u * 4);
                tt[u * 4 + 0] = __float2bfloat16(v0.x + v1.x);
                tt[u * 4 + 1] = __float2bfloat16(v0.y + v1.y);
                tt[u * 4 + 2] = __float2bfloat16(v0.z + v1.z);
                tt[u * 4 + 3] = __float2bfloat16(v0.w + v1.w);
            }
            *(uint4*)&As[ar * BK + ac] = *(const uint4*)tt;
        }
        gld_lds16(Bb + (long)lrow * 512 + (k0 + lcol),        (char*)Bs + wave * 1024);
        gld_lds16(Bb + (long)(64 + lrow) * 512 + (k0 + lcol), (char*)Bs + 4096 + wave * 1024);
        __builtin_amdgcn_s_waitcnt(0);
        __syncthreads();

        frag_t af[2], bfr[4];
#pragma unroll
        for (int i = 0; i < 2; i++) af[i]  = *(const frag_t*)&As[(wr + i * 16 + fr) * BK + fq];
#pragma unroll
        for (int j = 0; j < 4; j++) bfr[j] = *(const frag_t*)&Bs[(wc + j * 16 + fr) * BK + fq];
#pragma unroll
        for (int i = 0; i < 2; i++)
#pragma unroll
            for (int j = 0; j < 4; j++)
                acc[i][j] = mfma_16x16x32<frag_t>(af[i], bfr[j], acc[i][j]);
    }

    const int r0 = bm * 64 + wr + ((lane >> 4) << 2);
    const int c0 = bn * 128 + wc + fr;
#pragma unroll
    for (int j = 0; j < 4; j++) {
        const int c = c0 + j * 16;
        const float bv = __bfloat162float(bias[c]);
#pragma unroll
        for (int i = 0; i < 2; i++)
#pragma unroll
            for (int r = 0; r < 4; r++) {
                const long rg = r0 + i * 16 + r;
                out[rg * 512 + c] = acc[i][j][r] + bv;
            }
    }
}

// ---------------------------------------------------------------------------
// Fused flash attention, PHASE-SPLIT grid. SWAPPED QK (mfma(K,Q)): C rows = k,
// cols = q -> each lane owns one q-row with adjacent-k regs. P~ = exp2 (no max;
// logits pre-scaled 0.125*log2e), packed to bf16 pairs in-register, staged via
// a tiny XOR-swizzled packed LDS buffer (4 b64 writes + 2 b128 reads per it).
// kf/gf LDS reads hoisted across both it-tiles. Row-sums via MFMA vs ones.
// LDS exactly 40 KiB -> 4 blocks/CU; grid 1024 fully resident.
// ---------------------------------------------------------------------------
__global__ __launch_bounds__(256, 4)
void attn_fused(const bf16* __restrict__ q,    // [8192][512] (prescaled 0.125*log2e)
                const bf16* __restrict__ kb,   // [64][2176][64]
                const bf16* __restrict__ Skb,  // [64][1152][64]
                const bf16* __restrict__ GTS,  // [64][128][3136]
                float* __restrict__ out0,      // [8192][512] f32 phase0 partial
                float* __restrict__ out1)      // [8192][512] f32 phase1 partial
{
    __shared__ __align__(16) bf16 Ks[2][64 * 64];     // 16 KB (Q staged here at init)
    __shared__ __align__(16) bf16 Gs[2][64 * 64];     // 16 KB
    __shared__ __align__(16) unsigned Psw[4][16][32]; // 8 KB packed P~ (swizzled)

    const int t = threadIdx.x;
    const int w = t >> 6, lane = t & 63;
    const int bh = blockIdx.x, bm = blockIdx.y;
    const int phase = blockIdx.z;
    const int b = bh >> 3, h = bh & 7;
    const int g  = lane >> 4;        // 0..3
    const int fr = lane & 15;

    // stage Q[128][64] linear into Ks region, read qf frags once
    const bf16* Qg = q + ((long)(b * 1024 + bm * 128)) * 512 + h * 64;
    {
        const int qr = t >> 3, qc0 = (t & 7) << 3;
#pragma unroll
        for (int u = 0; u < 4; u++)
            gld_lds16(Qg + (long)(u * 32 + qr) * 512 + qc0, (char*)Ks + u * 4096 + w * 1024);
    }
    __builtin_amdgcn_s_waitcnt(0);
    __syncthreads();

    frag_t qf[2][2];
#pragma unroll
    for (int it = 0; it < 2; it++)
#pragma unroll
        for (int kh = 0; kh < 2; kh++)
            qf[it][kh] = *(const frag_t*)&((const bf16*)Ks)[(w * 32 + it * 16 + fr) * 64 + kh * 32 + g * 8];
    __syncthreads();   // all qf reads done before Ks restage

    // all-ones bf16 B-fragment for row-sum MFMA
    union { frag_t f; short s[8]; } ou;
#pragma unroll
    for (int i = 0; i < 8; i++) ou.s[i] = 0x3F80;
    const frag_t onesf = ou.f;

    const f32x4 vzero = {0.f, 0.f, 0.f, 0.f};
    const int rs = t >> 3, gs = t & 7;              // stage: row, phys group
    const int glo = gs ^ (rs & 7);                  // logical group (involution)

    const bf16* Kb = phase ? Skb + (long)bh * 1152 * 64 : kb + (long)bh * 2176 * 64;
    const bf16* Gb = GTS + (long)bh * 128 * 3136 + (phase ? 2080 : 0);
    const int NC = phase ? 17 : 33;
    const int valid = phase ? 1027 : 2051;

    f32x4 oacc[2][4];
    f32x4 lacc[2];
#pragma unroll
    for (int it = 0; it < 2; it++) {
        lacc[it] = vzero;
#pragma unroll
        for (int dt = 0; dt < 4; dt++) oacc[it][dt] = vzero;
    }

    // prologue: stage chunk 0 into buffer 0
    gld_lds16(Kb + (long)rs * 64 + glo * 8,          (char*)Ks[0] + w * 1024);
    gld_lds16(Kb + (long)(32 + rs) * 64 + glo * 8,   (char*)Ks[0] + 4096 + w * 1024);
    gld_lds16(Gb + (long)rs * 3136 + glo * 8,        (char*)Gs[0] + w * 1024);
    gld_lds16(Gb + (long)(32 + rs) * 3136 + glo * 8, (char*)Gs[0] + 4096 + w * 1024);

    unsigned* prow = &Psw[w][fr][0];
    const int swzk = (fr & 7) << 2;

    for (int c = 0; c < NC; c++) {
        const int buf = c & 1;
        __builtin_amdgcn_s_waitcnt(0);   // my stage for chunk c done
        __syncthreads();                  // everyone's done; prev-buf reads done
        if (c + 1 < NC) {                 // prefetch next chunk (hidden under compute)
            const bf16* Kc = Kb + (long)(c + 1) * 64 * 64;
            const bf16* Gc = Gb + (c + 1) * 64;
            gld_lds16(Kc + (long)rs * 64 + glo * 8,          (char*)Ks[buf ^ 1] + w * 1024);
            gld_lds16(Kc + (long)(32 + rs) * 64 + glo * 8,   (char*)Ks[buf ^ 1] + 4096 + w * 1024);
            gld_lds16(Gc + (long)rs * 3136 + glo * 8,        (char*)Gs[buf ^ 1] + w * 1024);
            gld_lds16(Gc + (long)(32 + rs) * 3136 + glo * 8, (char*)Gs[buf ^ 1] + 4096 + w * 1024);
        }
        const bf16* Kl = Ks[buf];
        const bf16* Gl = Gs[buf];

        // QK^T swapped: s2[it][ct], C rows = k (ct*16+4g+r), cols = q (fr)
        f32x4 s2[2][4];
#pragma unroll
        for (int it = 0; it < 2; it++)
#pragma unroll
            for (int ct = 0; ct < 4; ct++) s2[it][ct] = vzero;
        __builtin_amdgcn_s_setprio(1);
#pragma unroll
        for (int ct = 0; ct < 4; ct++)
#pragma unroll
            for (int kh = 0; kh < 2; kh++) {
                const int gph = (kh * 4 + g) ^ (fr & 7);
                const frag_t kf = *(const frag_t*)&Kl[(ct * 16 + fr) * 64 + gph * 8];
                s2[0][ct] = mfma_16x16x32<frag_t>(kf, qf[0][kh], s2[0][ct]);
                s2[1][ct] = mfma_16x16x32<frag_t>(kf, qf[1][kh], s2[1][ct]);
            }
        __builtin_amdgcn_s_setprio(0);

        if (c == NC - 1) {   // mask padded k rows (only last chunk has any)
#pragma unroll
            for (int ct = 0; ct < 4; ct++)
#pragma unroll
                for (int r = 0; r < 4; r++) {
                    const int kAbs = c * 64 + ct * 16 + 4 * g + r;
                    if (kAbs >= valid) { s2[0][ct][r] = -1.0e30f; s2[1][ct][r] = -1.0e30f; }
                }
        }

        // per it-tile: exp2, pack pairs, swizzled b64 store, b128 read of A-frags
        frag_t pa[2][2];
#pragma unroll
        for (int it = 0; it < 2; it++) {
#pragma unroll
            for (int ct = 0; ct < 4; ct++) {
                const unsigned w0 = pack2(exp2f(s2[it][ct][0]), exp2f(s2[it][ct][1]));
                const unsigned w1 = pack2(exp2f(s2[it][ct][2]), exp2f(s2[it][ct][3]));
                *(uint2*)&prow[(ct * 8 + 2 * g) ^ swzk] = make_uint2(w0, w1);
            }
#pragma unroll
            for (int kh = 0; kh < 2; kh++)
                pa[it][kh] = *(const frag_t*)&prow[(kh * 16 + 4 * g) ^ swzk];
        }

        // PV + row-sum: A = P~ (q-rows lane-local), B = G^T rows / ones
        __builtin_amdgcn_s_setprio(1);
#pragma unroll
        for (int kh = 0; kh < 2; kh++) {
            lacc[0] = mfma_16x16x32<frag_t>(pa[0][kh], onesf, lacc[0]);
            lacc[1] = mfma_16x16x32<frag_t>(pa[1][kh], onesf, lacc[1]);
#pragma unroll
            for (int dt = 0; dt < 4; dt++) {
                const int gph = (kh * 4 + g) ^ (fr & 7);
                const frag_t gf = *(const frag_t*)&Gl[(dt * 16 + fr) * 64 + gph * 8];
                oacc[0][dt] = mfma_16x16x32<frag_t>(pa[0][kh], gf, oacc[0][dt]);
                oacc[1][dt] = mfma_16x16x32<frag_t>(pa[1][kh], gf, oacc[1][dt]);
            }
        }
        __builtin_amdgcn_s_setprio(0);
    }

    // epilogue: out = oacc / l (+ G bias col for phase 0), f32 partial store
    float gba[4] = {0.f, 0.f, 0.f, 0.f};
    if (phase == 0) {
        const bf16* gp = GTS + (long)bh * 128 * 3136 + 2051;
#pragma unroll
        for (int dt = 0; dt < 4; dt++)
            gba[dt] = __bfloat162float(gp[(long)(dt * 16 + fr) * 3136]);
    }
    float* Og = (phase ? out1 : out0) + ((long)(b * 1024 + bm * 128)) * 512 + h * 64;
#pragma unroll
    for (int it = 0; it < 2; it++)
#pragma unroll
        for (int r = 0; r < 4; r++) {
            const float inv = 1.f / lacc[it][r];
#pragma unroll
            for (int dt = 0; dt < 4; dt++) {
                Og[(long)(w * 32 + it * 16 + g * 4 + r) * 512 + dt * 16 + fr] =
                    oacc[it][dt][r] * inv + gba[dt];
            }
        }
}

extern "C" void kernel_launch(void* const* d_in, const int* in_sizes, int n_in,
                              void* d_out, int out_size, void* d_ws, size_t ws_size,
                              hipStream_t stream)
{
    const void* inp  = d_in[0];
    const void* x    = d_in[1];
    const void* y    = d_in[2];
    const void* Wq   = d_in[3];
    const void* bq   = d_in[4];
    const void* Wkv  = d_in[5];
    const void* bkv  = d_in[6];
    const void* Wf   = d_in[7];
    const void* bff  = d_in[8];
    const void* Wo   = d_in[9];
    const void* bo   = d_in[10];
    const void* m_k  = d_in[11];
    // d_in[12] = m_v : dead code (v never used by the reference)
    const void* Sm_k = d_in[13];
    const void* Sm_v = d_in[14];

    char* ws = (char*)d_ws;
    bf16* WqB  = (bf16*)(ws + 256);        // [512][512]  (pre-scaled 0.125*log2e)
    bf16* WkvB = (bf16*)(ws + 524544);     // [1024][512] (contiguous -> [1536][512])
    bf16* WoB  = (bf16*)(ws + 1573120);    // [512][512]
    bf16* WfT  = (bf16*)(ws + 2097408);    // [2176][1056] Wf^T (+bf row 2051)
    bf16* bqB  = (bf16*)(ws + 6693120);    // [512] (pre-scaled; contiguous with bkvB)
    bf16* bkvB = (bf16*)(ws + 6694144);    // [1024]
    bf16* boB  = (bf16*)(ws + 6696192);    // [512]
    bf16* qb   = (bf16*)(ws + 6706432);    // [8192][512]
    bf16* kb   = (bf16*)(ws + 15095040);   // [64][2176][64]
    bf16* Skb  = (bf16*)(ws + 32920832);   // [64][1152][64]
    bf16* GTS  = (bf16*)(ws + 42358016);   // [64][128][3136]: [0,2080)=G^T, [2080,3136)=Sv^T
    char* OV   = ws + 93738240;

    // overlay lifetimes (stream order):
    //   inpB [8192][512] bf16 @OV           : dies after qkv gemm
    //   SvC  [4096][1056] bf16 @OV+16777216 : dies after gtck (GT reads it)
    //   ctxB [16384][512] bf16 @OV+33554432 : own region (written by prep_all)
    //   out0f/out1f [8192][512] f32 @OV / @OV+16777216 : attn outputs
    bf16*  inpB  = (bf16*)(OV);
    bf16*  SvC   = (bf16*)(OV + 16777216);
    bf16*  ctxB  = (bf16*)(OV + 33554432);
    float* out0f = (float*)(OV);
    float* out1f = (float*)(OV + 16777216);
    // total ws need: 93,738,240 + 50,331,648 = 144,069,888 (proven available)

    const dim3 blk(256);
    const float QS = 0.125f * 1.44269504f;   // fold softmax scale * log2(e) into q

    // 1) ONE prep kernel: dtype probe inlined; inputs + weights + WfT + biases
    //    + token/zero prefill of kb/Skb/SvT/SvC
    prep_all<<<dim3(8357), blk, 0, stream>>>(inp, x, y, Wq, Wkv, Wo, Wf, bff,
                                             bq, bkv, bo, m_k, Sm_k, Sm_v,
                                             inpB, ctxB, WqB, WkvB, WoB, WfT,
                                             bqB, bkvB, boB, kb, Skb, GTS, SvC, QS);

    // 2) merged qkv GEMM with fused scatter (TN=128, 768 blocks = 3/CU)
    gemm_qkv<<<dim3(12, 64), blk, 0, stream>>>(inpB, WqB, bqB, qb, Skb, GTS, SvC);

    // 3) GT + Ck packed into one dispatch (544 + 512 = 1056 blocks = 4.1/CU)
    gemm_gtck<<<dim3(1056), blk, 0, stream>>>(WfT, SvC, GTS, ctxB, WkvB, bkvB, kb);

    // 4) fused attention, phase-split grid (1024 blocks, 4 blocks/CU): f32 partials
    attn_fused<<<dim3(64, 8, 2), blk, 0, stream>>>(qb, kb, Skb, GTS, out0f, out1f);

    // 5) final = bf16(out0f+out1f) @ Wo^T + bo -> d_out (f32); TM=64 grid (4,128)
    gemm_final64<<<dim3(4, 128), blk, 0, stream>>>(out0f, out1f, WoB, boB, (float*)d_out);
}